// Round 3
// baseline (132.242 us; speedup 1.0000x reference)
//
#include <hip/hip_runtime.h>

#define N_MICS  192
#define OVERLAP 1024
#define WINDOW  524288
#define ROWLEN  (OVERLAP + WINDOW)
#define SPT     4
#define BLK     256

__global__ __launch_bounds__(BLK) void tdbf_kernel(
    const float* __restrict__ pos,
    const float* __restrict__ mic_pos,
    const float* __restrict__ buf,
    float* __restrict__ out)
{
    __shared__ float s_dist[N_MICS];
    __shared__ int   s_r[N_MICS];
    __shared__ int   s_offA[N_MICS];   // unsorted
    __shared__ float s_dfA[N_MICS];
    __shared__ int   s_off[N_MICS];    // r-grouped
    __shared__ float s_df[N_MICS];
    __shared__ int   s_cnt[4];
    __shared__ int   s_start[5];

    const int tid = threadIdx.x;

    // ---- distances (exact f32 replication of numpy) ----
    if (tid < N_MICS) {
        float dx = __fsub_rn(pos[0], mic_pos[tid * 3 + 0]);
        float dy = __fsub_rn(pos[1], mic_pos[tid * 3 + 1]);
        float dz = __fsub_rn(pos[2], mic_pos[tid * 3 + 2]);
        float ss = __fadd_rn(__fadd_rn(__fmul_rn(dx, dx), __fmul_rn(dy, dy)),
                             __fmul_rn(dz, dz));
        s_dist[tid] = __fsqrt_rn(ss);
    }
    __syncthreads();
    if (tid < N_MICS) {
        float mx = s_dist[0];
        for (int i = 1; i < N_MICS; ++i) mx = fmaxf(mx, s_dist[i]);
        float dd = __fsub_rn(s_dist[tid], mx);              // <= 0
        float delay = __fmul_rn(
                          __fmul_rn(__fdiv_rn(-dd, 343000.0f), 768000.0f),
                          0.0625f);                         // /16 exact
        int di = (int)delay;                                // trunc, delay >= 0
        int off = tid * ROWLEN + OVERLAP - di;
        s_offA[tid] = off;
        s_dfA[tid]  = __fsub_rn(delay, (float)di);
        s_r[tid]    = (off - 1) & 3;                        // block-uniform per mic
    }
    __syncthreads();
    // counts per r (threads 0..3)
    if (tid < 4) {
        int c = 0;
        for (int j = 0; j < N_MICS; ++j) c += (s_r[j] == tid);
        s_cnt[tid] = c;
    }
    __syncthreads();
    if (tid == 0) {
        s_start[0] = 0;
        for (int g = 0; g < 4; ++g) s_start[g + 1] = s_start[g] + s_cnt[g];
    }
    __syncthreads();
    // deterministic stable placement: rank = #mics j<tid with same r
    if (tid < N_MICS) {
        const int myr = s_r[tid];
        int rank = 0;
        for (int j = 0; j < N_MICS; ++j) rank += (j < tid) & (s_r[j] == myr);
        const int p = s_start[myr] + rank;
        s_off[p] = s_offA[tid];
        s_df[p]  = s_dfA[tid];
    }
    __syncthreads();

    // ---- main beamform: 4 samples/thread, mics grouped by alignment r ----
    const int t4 = (blockIdx.x * BLK + tid) * SPT;
    float a0 = 0.0f, a1 = 0.0f, a2 = 0.0f, a3 = 0.0f;

    #pragma unroll
    for (int g = 0; g < 4; ++g) {
        const int iBeg = __builtin_amdgcn_readfirstlane(s_start[g]);
        const int iEnd = __builtin_amdgcn_readfirstlane(s_start[g + 1]);
        #pragma unroll 4
        for (int i = iBeg; i < iEnd; ++i) {
            const int   off = __builtin_amdgcn_readfirstlane(s_off[i]);
            const float f   = __uint_as_float(
                                  __builtin_amdgcn_readfirstlane(__float_as_uint(s_df[i])));
            // A = element index of w[0]; (off-1-g) % 4 == 0 and t4 % 4 == 0 -> 16B aligned
            const int A = off + t4 - 1 - g;
            const float4 wa = *reinterpret_cast<const float4*>(buf + A);
            const float4 wb = *reinterpret_cast<const float4*>(buf + A + 4);
            float vm1, v0, v1, v2, v3;
            if      (g == 0) { vm1 = wa.x; v0 = wa.y; v1 = wa.z; v2 = wa.w; v3 = wb.x; }
            else if (g == 1) { vm1 = wa.y; v0 = wa.z; v1 = wa.w; v2 = wb.x; v3 = wb.y; }
            else if (g == 2) { vm1 = wa.z; v0 = wa.w; v1 = wb.x; v2 = wb.y; v3 = wb.z; }
            else             { vm1 = wa.w; v0 = wb.x; v1 = wb.y; v2 = wb.z; v3 = wb.w; }
            const float gg = 1.0f - f;
            a0 = fmaf(v0, gg, fmaf(vm1, f, a0));
            a1 = fmaf(v1, gg, fmaf(v0,  f, a1));
            a2 = fmaf(v2, gg, fmaf(v1,  f, a2));
            a3 = fmaf(v3, gg, fmaf(v2,  f, a3));
        }
    }

    const float inv = 1.0f / (float)N_MICS;
    float4 o;
    o.x = a0 * inv; o.y = a1 * inv; o.z = a2 * inv; o.w = a3 * inv;
    *reinterpret_cast<float4*>(out + t4) = o;
}

extern "C" void kernel_launch(void* const* d_in, const int* in_sizes, int n_in,
                              void* d_out, int out_size, void* d_ws, size_t ws_size,
                              hipStream_t stream) {
    const float* pos     = (const float*)d_in[0];
    const float* mic_pos = (const float*)d_in[1];
    const float* buf     = (const float*)d_in[2];
    float* out           = (float*)d_out;

    dim3 grid(WINDOW / (BLK * SPT));   // 512 blocks
    dim3 block(BLK);
    tdbf_kernel<<<grid, block, 0, stream>>>(pos, mic_pos, buf, out);
}

// Round 4
// 82.204 us; speedup vs baseline: 1.6087x; 1.6087x over previous
//
#include <hip/hip_runtime.h>

#define N_MICS  192
#define OVERLAP 1024
#define WINDOW  524288
#define ROWLEN  (OVERLAP + WINDOW)
#define BLK     256

// ---------------- shared preamble (exact f32 replication of numpy) --------
__device__ __forceinline__ void compute_delays(
    const float* __restrict__ pos, const float* __restrict__ mic_pos,
    float* s_dist, int* s_off, float* s_df, int tid)
{
    if (tid < N_MICS) {
        float dx = __fsub_rn(pos[0], mic_pos[tid * 3 + 0]);
        float dy = __fsub_rn(pos[1], mic_pos[tid * 3 + 1]);
        float dz = __fsub_rn(pos[2], mic_pos[tid * 3 + 2]);
        float ss = __fadd_rn(__fadd_rn(__fmul_rn(dx, dx), __fmul_rn(dy, dy)),
                             __fmul_rn(dz, dz));
        s_dist[tid] = __fsqrt_rn(ss);
    }
    __syncthreads();
    if (tid < N_MICS) {
        float mx = s_dist[0];
        for (int i = 1; i < N_MICS; ++i) mx = fmaxf(mx, s_dist[i]);
        float dd = __fsub_rn(s_dist[tid], mx);              // <= 0
        float delay = __fmul_rn(
                          __fmul_rn(__fdiv_rn(-dd, 343000.0f), 768000.0f),
                          0.0625f);                         // /16 exact
        int di = (int)delay;                                // trunc, delay >= 0
        s_off[tid] = tid * ROWLEN + OVERLAP - di;
        s_df[tid]  = __fsub_rn(delay, (float)di);
    }
    __syncthreads();
}

#define RFL_I(x) __builtin_amdgcn_readfirstlane(x)
#define RFL_F(x) __uint_as_float(__builtin_amdgcn_readfirstlane(__float_as_uint(x)))

// ---------------- main: SPT=8, mics split 2-way across block parity -------
__global__ __launch_bounds__(BLK) void tdbf_partial(
    const float* __restrict__ pos,
    const float* __restrict__ mic_pos,
    const float* __restrict__ buf,
    float* __restrict__ ws)
{
    __shared__ float s_dist[N_MICS];
    __shared__ int   s_off[N_MICS];
    __shared__ float s_df[N_MICS];
    const int tid = threadIdx.x;
    compute_delays(pos, mic_pos, s_dist, s_off, s_df, tid);

    const int half = blockIdx.x & 1;
    const int tblk = blockIdx.x >> 1;
    const int t8   = (tblk * BLK + tid) * 8;
    const int mBeg = half * (N_MICS / 2);

    float a0 = 0.f, a1 = 0.f, a2 = 0.f, a3 = 0.f;
    float a4 = 0.f, a5 = 0.f, a6 = 0.f, a7 = 0.f;

    #pragma unroll 4
    for (int mi = 0; mi < N_MICS / 2; ++mi) {
        const int   off = RFL_I(s_off[mBeg + mi]);
        const float f   = RFL_F(s_df[mBeg + mi]);
        const float* p  = buf + off + t8;
        const float vm1 = p[-1];
        const float v0 = p[0], v1 = p[1], v2 = p[2], v3 = p[3];
        const float v4 = p[4], v5 = p[5], v6 = p[6], v7 = p[7];
        const float g  = 1.0f - f;
        a0 = fmaf(v0, g, fmaf(vm1, f, a0));
        a1 = fmaf(v1, g, fmaf(v0,  f, a1));
        a2 = fmaf(v2, g, fmaf(v1,  f, a2));
        a3 = fmaf(v3, g, fmaf(v2,  f, a3));
        a4 = fmaf(v4, g, fmaf(v3,  f, a4));
        a5 = fmaf(v5, g, fmaf(v4,  f, a5));
        a6 = fmaf(v6, g, fmaf(v5,  f, a6));
        a7 = fmaf(v7, g, fmaf(v6,  f, a7));
    }

    float* w = ws + (size_t)half * WINDOW + t8;
    float4 o0; o0.x = a0; o0.y = a1; o0.z = a2; o0.w = a3;
    float4 o1; o1.x = a4; o1.y = a5; o1.z = a6; o1.w = a7;
    *reinterpret_cast<float4*>(w)     = o0;
    *reinterpret_cast<float4*>(w + 4) = o1;
}

__global__ __launch_bounds__(BLK) void tdbf_reduce(
    const float* __restrict__ ws, float* __restrict__ out)
{
    const int i = (blockIdx.x * BLK + threadIdx.x) * 4;
    const float4 x = *reinterpret_cast<const float4*>(ws + i);
    const float4 y = *reinterpret_cast<const float4*>(ws + WINDOW + i);
    const float inv = 1.0f / (float)N_MICS;
    float4 o;
    o.x = (x.x + y.x) * inv;
    o.y = (x.y + y.y) * inv;
    o.z = (x.z + y.z) * inv;
    o.w = (x.w + y.w) * inv;
    *reinterpret_cast<float4*>(out + i) = o;
}

// ---------------- fallback: round-2 proven kernel (SPT=4, no ws) ----------
__global__ __launch_bounds__(BLK) void tdbf_mono(
    const float* __restrict__ pos,
    const float* __restrict__ mic_pos,
    const float* __restrict__ buf,
    float* __restrict__ out)
{
    __shared__ float s_dist[N_MICS];
    __shared__ int   s_off[N_MICS];
    __shared__ float s_df[N_MICS];
    const int tid = threadIdx.x;
    compute_delays(pos, mic_pos, s_dist, s_off, s_df, tid);

    const int t4 = (blockIdx.x * BLK + tid) * 4;
    float a0 = 0.f, a1 = 0.f, a2 = 0.f, a3 = 0.f;
    #pragma unroll 6
    for (int m = 0; m < N_MICS; ++m) {
        const int   off = RFL_I(s_off[m]);
        const float f   = RFL_F(s_df[m]);
        const float* p  = buf + off + t4;
        const float vm1 = p[-1];
        const float v0 = p[0], v1 = p[1], v2 = p[2], v3 = p[3];
        const float g  = 1.0f - f;
        a0 = fmaf(v0, g, fmaf(vm1, f, a0));
        a1 = fmaf(v1, g, fmaf(v0,  f, a1));
        a2 = fmaf(v2, g, fmaf(v1,  f, a2));
        a3 = fmaf(v3, g, fmaf(v2,  f, a3));
    }
    const float inv = 1.0f / (float)N_MICS;
    float4 o; o.x = a0 * inv; o.y = a1 * inv; o.z = a2 * inv; o.w = a3 * inv;
    *reinterpret_cast<float4*>(out + t4) = o;
}

extern "C" void kernel_launch(void* const* d_in, const int* in_sizes, int n_in,
                              void* d_out, int out_size, void* d_ws, size_t ws_size,
                              hipStream_t stream) {
    const float* pos     = (const float*)d_in[0];
    const float* mic_pos = (const float*)d_in[1];
    const float* buf     = (const float*)d_in[2];
    float* out           = (float*)d_out;

    const size_t ws_needed = (size_t)2 * WINDOW * sizeof(float);
    if (ws_size >= ws_needed) {
        float* ws = (float*)d_ws;
        dim3 grid(2 * WINDOW / (BLK * 8));   // 512 blocks (256 t-blocks x 2 halves)
        tdbf_partial<<<grid, dim3(BLK), 0, stream>>>(pos, mic_pos, buf, ws);
        dim3 rgrid(WINDOW / (BLK * 4));      // 512 blocks
        tdbf_reduce<<<rgrid, dim3(BLK), 0, stream>>>(ws, out);
    } else {
        dim3 grid(WINDOW / (BLK * 4));       // 512 blocks
        tdbf_mono<<<grid, dim3(BLK), 0, stream>>>(pos, mic_pos, buf, out);
    }
}